// Round 8
// baseline (286.841 us; speedup 1.0000x reference)
//
#include <hip/hip_runtime.h>
#include <math.h>

#define HW 9216
#define WD 96
#define NC 128

typedef unsigned short u16;
typedef __attribute__((ext_vector_type(8))) short short8;
typedef __attribute__((ext_vector_type(4))) float v4f;

__device__ __forceinline__ int rfl(int v){ return __builtin_amdgcn_readfirstlane(v); }
__device__ __forceinline__ float bu2f(u16 s){ return __uint_as_float(((unsigned)s)<<16); }
__device__ __forceinline__ u16 f2b(float f){ unsigned u = __float_as_uint(f);
  return (u16)((u + 0x7fffu + ((u>>16)&1u))>>16); }

// ---------------- K0: weight prep ----------------
__global__ __launch_bounds__(256) void prep_weights(const float* __restrict__ pw_w,
    const float* __restrict__ off_w, const float* __restrict__ dc_w,
    u16* __restrict__ wpwb, u16* __restrict__ wob, u16* __restrict__ wdcb){
  int t = blockIdx.x*256 + threadIdx.x;
  if (t < 16384) wpwb[t] = f2b(pw_w[t]);
  if (t < 36864){ int o = t/1152, r = t - o*1152; int k = r>>7, c = r&127;
                  wob[t] = (o<18) ? f2b(off_w[(o*128+c)*9+k]) : (u16)0; }
  if (t < 147456){ int o = t/1152, r = t - o*1152; int k = r>>7, c = r&127;
                   wdcb[t] = f2b(dc_w[(o*128+c)*9 + k]); }
}

// ---------------- K1: depthwise 3x3 + bias (NCHW fp32) ----------------
__global__ __launch_bounds__(256) void dw_conv(const float* __restrict__ x,
    const float* __restrict__ w, const float* __restrict__ bias, float* __restrict__ h1){
  int n = blockIdx.x*256 + threadIdx.x;
  int bc = rfl(n / HW);
  int p = n - bc*HW;
  int c = bc & 127;
  int yy = p / WD, xx = p - (p/WD)*WD;
  const float* xc = x + (size_t)bc*HW;
  float acc = bias[c];
  #pragma unroll
  for (int r=0;r<3;r++){
    int y2 = yy + r - 1;
    #pragma unroll
    for (int cc2=0;cc2<3;cc2++){
      int x2 = xx + cc2 - 1;
      if (y2>=0 && y2<96 && x2>=0 && x2<96)
        acc = fmaf(w[c*9 + r*3 + cc2], xc[y2*WD + x2], acc);
    }
  }
  h1[n] = acc;
}

// ---------------- K2: pointwise 1x1 via MFMA ----------------
__global__ __launch_bounds__(256) void pw_mfma(const float* __restrict__ h1,
    const u16* __restrict__ wpwb, const float* __restrict__ pw_b, float* __restrict__ h2){
  __shared__ short Aw[128*136];
  __shared__ short Bw[128*68];
  int blk = blockIdx.x; int row0 = blk*64;
  int b = rfl(row0/HW); int pbase = rfl(row0 - b*HW);
  int t = threadIdx.x;
  #pragma unroll
  for (int i=0;i<8;i++){
    int idx = i*256 + t; int o = idx>>4, seg = idx&15;
    *(short8*)&Aw[o*136 + seg*8] = *(const short8*)(wpwb + o*128 + seg*8);
  }
  #pragma unroll
  for (int i=0;i<8;i++){
    int idx = i*256 + t; int c = idx>>4, seg = idx&15;
    float4 v = *(const float4*)(h1 + (size_t)(b*NC+c)*HW + pbase + seg*4);
    ushort4 pk = make_ushort4(f2b(v.x), f2b(v.y), f2b(v.z), f2b(v.w));
    *(ushort4*)&Bw[c*68 + seg*4] = pk;
  }
  __syncthreads();
  int w = rfl(t>>6); int l = t&63; int q = l>>4; int ln = l&15;
  v4f acc[8];
  #pragma unroll
  for (int mt=0;mt<8;mt++) acc[mt] = (v4f){0.f,0.f,0.f,0.f};
  #pragma unroll
  for (int ks=0;ks<4;ks++){
    short8 bf;
    #pragma unroll
    for (int j=0;j<8;j++) bf[j] = Bw[(ks*32 + q*8 + j)*68 + w*16 + ln];
    #pragma unroll
    for (int mt=0;mt<8;mt++){
      short8 af = *(short8*)&Aw[(mt*16+ln)*136 + ks*32 + q*8];
      acc[mt] = __builtin_amdgcn_mfma_f32_16x16x32_bf16(af, bf, acc[mt], 0,0,0);
    }
  }
  int px = pbase + w*16 + ln;
  #pragma unroll
  for (int mt=0;mt<8;mt++){
    #pragma unroll
    for (int r=0;r<4;r++){
      int o = mt*16 + q*4 + r;
      h2[(size_t)(b*NC+o)*HW + px] = acc[mt][r] + pw_b[o];
    }
  }
}

// ---------------- K3: InstanceNorm stats ----------------
__global__ __launch_bounds__(256) void inorm_stats(const float* __restrict__ h2, float* __restrict__ st){
  int bc = blockIdx.x;
  const float* src = h2 + (size_t)bc*HW;
  float s=0.f, ss=0.f;
  for (int i=threadIdx.x; i<HW; i+=256){ float v=src[i]; s+=v; ss=fmaf(v,v,ss); }
  #pragma unroll
  for (int off=32; off; off>>=1){ s += __shfl_down(s,off); ss += __shfl_down(ss,off); }
  __shared__ float rsm[2][4];
  int wave = threadIdx.x>>6, lane = threadIdx.x&63;
  if (lane==0){ rsm[0][wave]=s; rsm[1][wave]=ss; }
  __syncthreads();
  if (threadIdx.x==0){
    float S = rsm[0][0]+rsm[0][1]+rsm[0][2]+rsm[0][3];
    float SS= rsm[1][0]+rsm[1][1]+rsm[1][2]+rsm[1][3];
    float mu = S * (1.f/9216.f);
    float var = SS * (1.f/9216.f) - mu*mu;
    st[bc*2]   = mu;
    st[bc*2+1] = rsqrtf(var + 1e-5f);
  }
}

// ---------------- K4: dsc (NCHW fp32) + dscT/dscL (NHWC bf16 hi/lo) ----------------
__global__ __launch_bounds__(256) void make_dsc(const float* __restrict__ h2,
    const float* __restrict__ st, float* __restrict__ dsc,
    u16* __restrict__ dscT, u16* __restrict__ dscL){
  int blk = blockIdx.x;
  int pt = blk % 144; int r = blk/144; int ch = r & 1; int b = r >> 1;
  int c0 = ch*64, pbase = pt*64;
  __shared__ float tile[64][65];
  int tr = threadIdx.x >> 2;
  int g  = threadIdx.x & 3;
  int c  = c0 + tr;
  float mu = st[(b*128+c)*2];
  float rs = st[(b*128+c)*2+1];
  const float* src = h2 + (size_t)(b*128+c)*HW + pbase + g*16;
  float* d = dsc + (size_t)(b*128+c)*HW + pbase + g*16;
  #pragma unroll
  for (int i=0;i<4;i++){
    float4 v = *(const float4*)(src + i*4);
    v.x=(v.x-mu)*rs; v.y=(v.y-mu)*rs; v.z=(v.z-mu)*rs; v.w=(v.w-mu)*rs;
    *(float4*)(d + i*4) = v;
    tile[tr][g*16+i*4+0]=v.x; tile[tr][g*16+i*4+1]=v.y;
    tile[tr][g*16+i*4+2]=v.z; tile[tr][g*16+i*4+3]=v.w;
  }
  __syncthreads();
  int pr = tr;
  u16* dt = dscT + ((size_t)b*HW + pbase + pr)*NC + c0 + g*16;
  u16* dl = dscL + ((size_t)b*HW + pbase + pr)*NC + c0 + g*16;
  #pragma unroll
  for (int i=0;i<4;i++){
    float v0 = tile[g*16+i*4+0][pr], v1 = tile[g*16+i*4+1][pr];
    float v2 = tile[g*16+i*4+2][pr], v3 = tile[g*16+i*4+3][pr];
    ushort4 hi = make_ushort4(f2b(v0), f2b(v1), f2b(v2), f2b(v3));
    ushort4 lo = make_ushort4(f2b(v0-bu2f(hi.x)), f2b(v1-bu2f(hi.y)),
                              f2b(v2-bu2f(hi.z)), f2b(v3-bu2f(hi.w)));
    *(ushort4*)(dt + i*4) = hi;
    *(ushort4*)(dl + i*4) = lo;
  }
}

// ---------------- K5: offset conv, round-6 As protocol + per-lane B registers -----------
// Identical single-buffer A staging/barriers as round 6; only change: B tile comes from
// per-lane global reads (L2-hot wob) into a 2-set register pipeline (bregA/bregB).
__global__ __launch_bounds__(256) void off_mfma(const u16* __restrict__ dscT,
    const u16* __restrict__ dscL, const u16* __restrict__ wob,
    const float* __restrict__ off_b, float4* __restrict__ wg, ushort4* __restrict__ ad){
  __shared__ short As[2][32*40];             // hi/lo A tiles (32 px x 32 K)
  __shared__ float Po[18*32];
  int blk = blockIdx.x;                      // 1152 = 8 * 144
  int tile = (blk&7)*144 + (blk>>3);
  int row0 = tile*32;
  int b = rfl(row0/HW); int pbase = rfl(row0 - b*HW);
  int t = threadIdx.x;
  int apx = t>>3, hl = (t>>2)&1, segA = t&3;
  int w = rfl(t>>6); int l = t&63; int q = l>>4; int ln = l&15;
  int mt = w&1, ntl = w>>1;
  int P = pbase + apx;
  int py = P/96, px_ = P - 96*(P/96);
  const u16* gsrc = (hl ? dscL : dscT) + (size_t)b*HW*NC;
  const u16* wrow = wob + (ntl*16+ln)*1152 + q*8;
  uint4 rg; short8 bregA, bregB;
  auto prefetch = [&](int s){
    int k = s>>2, cseg = s&3;
    int y2 = py + k/3 - 1, x2 = px_ + k%3 - 1;
    bool valid = ((unsigned)y2 < 96u) && ((unsigned)x2 < 96u);
    int off = ((y2*96 + x2)*NC) + cseg*32 + segA*8;
    rg = valid ? *(const uint4*)(gsrc + off) : (uint4){0,0,0,0};
  };
  auto loadB = [&](int s)->short8{
    return *(const short8*)(wrow + (s>>2)*128 + (s&3)*32);
  };
  auto commit = [&](){
    *(short8*)&As[hl][apx*40 + segA*8] = *(short8*)&rg;
  };
  v4f acc = (v4f){0.f,0.f,0.f,0.f};
  auto step = [&](short8 bf){
    short8 ah = *(short8*)&As[0][(mt*16+ln)*40 + q*8];
    short8 al = *(short8*)&As[1][(mt*16+ln)*40 + q*8];
    acc = __builtin_amdgcn_mfma_f32_16x16x32_bf16(ah, bf, acc, 0,0,0);
    acc = __builtin_amdgcn_mfma_f32_16x16x32_bf16(al, bf, acc, 0,0,0);
  };
  prefetch(0); bregA = loadB(0); commit();
  __syncthreads();
  #pragma unroll 1
  for (int s=0;s<36;s+=2){
    if (s<35){ prefetch(s+1); bregB = loadB(s+1); }
    step(bregA);
    __syncthreads();
    if (s<35){ commit(); __syncthreads(); }
    if (s+2<36){ prefetch(s+2); bregA = loadB(s+2); }
    step(bregB);
    __syncthreads();
    if (s+2<36){ commit(); __syncthreads(); }
  }
  int o = ntl*16 + ln;
  if (o < 18){
    float ob = off_b[o];
    #pragma unroll
    for (int r=0;r<4;r++) Po[o*32 + mt*16 + q*4 + r] = acc[r] + ob;
  }
  __syncthreads();
  #pragma unroll
  for (int i=0;i<2;i++){
    int idx = i*256 + t;
    if (idx < 288){
      int pxl = idx & 31, k = idx >> 5;
      int Pp = pbase + pxl;
      float dy = Po[(2*k)*32 + pxl], dx = Po[(2*k+1)*32 + pxl];
      float ys = (float)(Pp/96 + k/3 - 1) + dy;
      float xs = (float)(Pp%96 + k%3 - 1) + dx;
      float fy0 = floorf(ys), fx0 = floorf(xs);
      float wy = ys - fy0, wx = xs - fx0;
      int y0 = (int)fy0, x0 = (int)fx0;
      int y1 = y0+1, x1 = x0+1;
      float vy0 = (y0>=0 && y0<=95) ? 1.f : 0.f;
      float vy1 = (y1>=0 && y1<=95) ? 1.f : 0.f;
      float vx0 = (x0>=0 && x0<=95) ? 1.f : 0.f;
      float vx1 = (x1>=0 && x1<=95) ? 1.f : 0.f;
      int y0c=min(max(y0,0),95), y1c=min(max(y1,0),95);
      int x0c=min(max(x0,0),95), x1c=min(max(x1,0),95);
      float4 w4;
      w4.x = (1.f-wy)*(1.f-wx)*vy0*vx0;
      w4.y = (1.f-wy)*wx*vy0*vx1;
      w4.z = wy*(1.f-wx)*vy1*vx0;
      w4.w = wy*wx*vy1*vx1;
      int gi = (b*9 + k)*HW + pbase + pxl;
      wg[gi] = w4;
      ad[gi] = make_ushort4((u16)(y0c*WD+x0c), (u16)(y0c*WD+x1c),
                            (u16)(y1c*WD+x0c), (u16)(y1c*WD+x1c));
    }
  }
}

// ---------------- K6: deform conv, round-6 As protocol + wg/ad LDS + per-lane B --------
// Identical single-buffer A staging/barriers as round 6; changes: (1) wg/ad preloaded
// into LDS once (indirection off the per-step chain); (2) B per-lane registers, 2-set.
__global__ __launch_bounds__(256) void deform_mfma(const u16* __restrict__ dscT,
    const u16* __restrict__ wdcb, const float* __restrict__ dc_b,
    const float4* __restrict__ wg, const ushort4* __restrict__ ad,
    float* __restrict__ dc_t){
  __shared__ short As[32*72];                // 32 px x 64 K (pad 72)
  __shared__ float4 WgL[288];                // [tap*32+px]
  __shared__ ushort4 AdL[288];
  int blk = blockIdx.x;                      // 1152 = 8 * 144
  int tile = (blk&7)*144 + (blk>>3);
  int row0 = tile*32;
  int b = rfl(row0/HW); int pbase = rfl(row0 - b*HW);
  int t = threadIdx.x;
  int apx = t>>3, cs8 = t&7;
  int w = rfl(t>>6); int l = t&63; int q = l>>4; int ln = l&15;
  int mt = w&1, nb = (w>>1)*4;
  const u16* db0 = dscT + (size_t)b*HW*NC + cs8*8;
  const u16* wrow = wdcb + q*8;
  #pragma unroll
  for (int i=0;i<2;i++){
    int idx = i*256 + t;
    if (idx < 288){ int k = idx>>5, pxl = idx&31; int gi = (b*9+k)*HW + pbase + pxl;
      WgL[idx] = wg[gi]; AdL[idx] = ad[gi]; }
  }
  __syncthreads();
  float4 wv; ushort4 av; uint4 r0,r1,r2,r3;
  short8 bregA[8], bregB[8];
  auto prefetch = [&](int s){
    int k = s>>1; int cb = (s&1)<<6;
    if (!(s&1)){ av = AdL[k*32+apx]; wv = WgL[k*32+apx]; }
    const u16* db = db0 + cb;
    r0 = *(const uint4*)(db + (int)av.x*NC);
    r1 = *(const uint4*)(db + (int)av.y*NC);
    r2 = *(const uint4*)(db + (int)av.z*NC);
    r3 = *(const uint4*)(db + (int)av.w*NC);
  };
  auto loadB = [&](int s, short8* dst){
    int k = s>>1, cb = (s&1)<<6;
    const u16* wp = wrow + k*128 + cb;
    #pragma unroll
    for (int nt=0;nt<4;nt++){
      #pragma unroll
      for (int ks=0;ks<2;ks++)
        dst[nt*2+ks] = *(const short8*)(wp + ((nb+nt)*16+ln)*1152 + ks*32);
    }
  };
  auto commit = [&](){
    const u16* pa=(const u16*)&r0; const u16* pb=(const u16*)&r1;
    const u16* pc=(const u16*)&r2; const u16* pd=(const u16*)&r3;
    short8 sv;
    #pragma unroll
    for (int j=0;j<8;j++){
      float f = wv.x*bu2f(pa[j]) + wv.y*bu2f(pb[j]) + wv.z*bu2f(pc[j]) + wv.w*bu2f(pd[j]);
      sv[j] = (short)f2b(f);
    }
    *(short8*)&As[apx*72 + cs8*8] = sv;
  };
  v4f acc[4];
  #pragma unroll
  for (int nt=0;nt<4;nt++) acc[nt] = (v4f){0.f,0.f,0.f,0.f};
  auto step = [&](const short8* bb){
    #pragma unroll
    for (int ks=0;ks<2;ks++){
      short8 af = *(const short8*)&As[(mt*16+ln)*72 + ks*32 + q*8];
      #pragma unroll
      for (int nt=0;nt<4;nt++)
        acc[nt] = __builtin_amdgcn_mfma_f32_16x16x32_bf16(af, bb[nt*2+ks], acc[nt], 0,0,0);
    }
  };
  prefetch(0); loadB(0, bregA); commit();
  __syncthreads();
  #pragma unroll 1
  for (int s=0;s<18;s+=2){
    if (s<17){ prefetch(s+1); loadB(s+1, bregB); }
    step(bregA);
    __syncthreads();
    if (s<17){ commit(); __syncthreads(); }
    if (s+2<18){ prefetch(s+2); loadB(s+2, bregA); }
    step(bregB);
    __syncthreads();
    if (s+2<18){ commit(); __syncthreads(); }
  }
  #pragma unroll
  for (int nt=0;nt<4;nt++){
    int o = (nb+nt)*16 + ln;
    float bias = dc_b[o];
    #pragma unroll
    for (int r=0;r<4;r++){
      int px = pbase + mt*16 + q*4 + r;
      dc_t[((size_t)b*HW + px)*NC + o] = acc[nt][r] + bias;
    }
  }
}

// ---------------- K7: channel LayerNorm + sigmoid gate + multiply ----------------
__global__ __launch_bounds__(256) void epilogue(const float* __restrict__ dc_t,
    const float* __restrict__ dsc, const float* __restrict__ ln_g,
    const float* __restrict__ ln_b, float* __restrict__ out){
  __shared__ float T[64*129];
  __shared__ float Ps[4*64], Qs[4*64], Ms[64], Rs[64];
  int blk = blockIdx.x;
  int b = rfl(blk/144); int pbase = rfl(blk - (blk/144)*144)*64;
  int t = threadIdx.x;
  #pragma unroll
  for (int i=0;i<8;i++){
    int idx = i*256 + t; int px = idx>>5, seg = idx&31;
    float4 v = *(const float4*)(dc_t + ((size_t)b*HW + pbase + px)*NC + seg*4);
    float* d = &T[px*129 + seg*4];
    d[0]=v.x; d[1]=v.y; d[2]=v.z; d[3]=v.w;
  }
  __syncthreads();
  int px = t&63, cg = t>>6;
  float s=0.f, ss=0.f;
  #pragma unroll
  for (int i=0;i<32;i++){ float v = T[px*129 + cg*32 + i]; s += v; ss = fmaf(v,v,ss); }
  Ps[cg*64+px] = s; Qs[cg*64+px] = ss;
  __syncthreads();
  if (t<64){
    float S = Ps[px]+Ps[64+px]+Ps[128+px]+Ps[192+px];
    float SS= Qs[px]+Qs[64+px]+Qs[128+px]+Qs[192+px];
    float m = S*(1.f/128.f);
    float var = SS*(1.f/128.f) - m*m;
    Ms[px] = m; Rs[px] = rsqrtf(var + 1e-5f);
  }
  __syncthreads();
  float m = Ms[px], rs = Rs[px];
  #pragma unroll 4
  for (int i=0;i<32;i++){
    int c = cg*32 + i;
    float ln = (T[px*129+c] - m)*rs*ln_g[c] + ln_b[c];
    float attn = 1.f/(1.f+__expf(-ln));
    size_t idx = (size_t)(b*NC+c)*HW + pbase + px;
    out[idx] = dsc[idx]*attn;
  }
}

extern "C" void kernel_launch(void* const* d_in, const int* in_sizes, int n_in,
                              void* d_out, int out_size, void* d_ws, size_t ws_size,
                              hipStream_t stream){
  const float* x    = (const float*)d_in[0];
  const float* dw_w = (const float*)d_in[1];
  const float* dw_b = (const float*)d_in[2];
  const float* pw_w = (const float*)d_in[3];
  const float* pw_b = (const float*)d_in[4];
  const float* off_w= (const float*)d_in[5];
  const float* off_b= (const float*)d_in[6];
  const float* dc_w = (const float*)d_in[7];
  const float* dc_b = (const float*)d_in[8];
  const float* ln_g = (const float*)d_in[9];
  const float* ln_b = (const float*)d_in[10];
  float* out = (float*)d_out;

  float* W    = (float*)d_ws;
  float*   bufA = W;                          // h1, then dsc (NCHW f32)
  float*   bufB = W + 4718592;                // h2, then dc_t (NHWC f32)
  u16*     dscT = (u16*)(W + 9437184);        // NHWC bf16 hi (4718592 u16)
  u16*     dscL = (u16*)(W + 11796480);       // NHWC bf16 lo residual
  float4*  wg   = (float4*)(W + 14155776);    // 331776 float4
  ushort4* ad   = (ushort4*)(W + 15482880);   // 331776 ushort4
  float*   st   = W + 16146432;
  u16*     wpwb = (u16*)(W + 16147456);       // 16384 u16
  u16*     wob  = (u16*)(W + 16155648);       // 36864 u16
  u16*     wdcb = (u16*)(W + 16174080);       // 147456 u16

  prep_weights<<<576, 256, 0, stream>>>(pw_w, off_w, dc_w, wpwb, wob, wdcb);
  dw_conv     <<<18432, 256, 0, stream>>>(x, dw_w, dw_b, bufA);
  pw_mfma     <<<576, 256, 0, stream>>>(bufA, wpwb, pw_b, bufB);
  inorm_stats <<<512, 256, 0, stream>>>(bufB, st);
  make_dsc    <<<1152, 256, 0, stream>>>(bufB, st, bufA, dscT, dscL);
  off_mfma    <<<1152, 256, 0, stream>>>(dscT, dscL, wob, off_b, wg, ad);
  deform_mfma <<<1152, 256, 0, stream>>>(dscT, wdcb, dc_b, wg, ad, bufB);
  epilogue    <<<576, 256, 0, stream>>>(bufB, bufA, ln_g, ln_b, out);
}

// Round 9
// 229.703 us; speedup vs baseline: 1.2488x; 1.2488x over previous
//
#include <hip/hip_runtime.h>
#include <math.h>

#define HW 9216
#define WD 96
#define NC 128

typedef unsigned short u16;
typedef __attribute__((ext_vector_type(8))) short short8;
typedef __attribute__((ext_vector_type(4))) float v4f;

__device__ __forceinline__ int rfl(int v){ return __builtin_amdgcn_readfirstlane(v); }
__device__ __forceinline__ float bu2f(u16 s){ return __uint_as_float(((unsigned)s)<<16); }
__device__ __forceinline__ u16 f2b(float f){ unsigned u = __float_as_uint(f);
  return (u16)((u + 0x7fffu + ((u>>16)&1u))>>16); }

// ---------------- K0: weight prep ----------------
__global__ __launch_bounds__(256) void prep_weights(const float* __restrict__ pw_w,
    const float* __restrict__ off_w, const float* __restrict__ dc_w,
    u16* __restrict__ wpwb, u16* __restrict__ wob, u16* __restrict__ wdcb){
  int t = blockIdx.x*256 + threadIdx.x;
  if (t < 16384) wpwb[t] = f2b(pw_w[t]);
  if (t < 36864){ int o = t/1152, r = t - o*1152; int k = r>>7, c = r&127;
                  wob[t] = (o<18) ? f2b(off_w[(o*128+c)*9+k]) : (u16)0; }
  if (t < 147456){ int o = t/1152, r = t - o*1152; int k = r>>7, c = r&127;
                   wdcb[t] = f2b(dc_w[(o*128+c)*9 + k]); }
}

// ---------------- K1: depthwise 3x3 + bias (NCHW fp32) ----------------
__global__ __launch_bounds__(256) void dw_conv(const float* __restrict__ x,
    const float* __restrict__ w, const float* __restrict__ bias, float* __restrict__ h1){
  int n = blockIdx.x*256 + threadIdx.x;
  int bc = rfl(n / HW);
  int p = n - bc*HW;
  int c = bc & 127;
  int yy = p / WD, xx = p - (p/WD)*WD;
  const float* xc = x + (size_t)bc*HW;
  float acc = bias[c];
  #pragma unroll
  for (int r=0;r<3;r++){
    int y2 = yy + r - 1;
    #pragma unroll
    for (int cc2=0;cc2<3;cc2++){
      int x2 = xx + cc2 - 1;
      if (y2>=0 && y2<96 && x2>=0 && x2<96)
        acc = fmaf(w[c*9 + r*3 + cc2], xc[y2*WD + x2], acc);
    }
  }
  h1[n] = acc;
}

// ---------------- K2: pointwise 1x1 via MFMA ----------------
__global__ __launch_bounds__(256) void pw_mfma(const float* __restrict__ h1,
    const u16* __restrict__ wpwb, const float* __restrict__ pw_b, float* __restrict__ h2){
  __shared__ short Aw[128*136];
  __shared__ short Bw[128*68];
  int blk = blockIdx.x; int row0 = blk*64;
  int b = rfl(row0/HW); int pbase = rfl(row0 - b*HW);
  int t = threadIdx.x;
  #pragma unroll
  for (int i=0;i<8;i++){
    int idx = i*256 + t; int o = idx>>4, seg = idx&15;
    *(short8*)&Aw[o*136 + seg*8] = *(const short8*)(wpwb + o*128 + seg*8);
  }
  #pragma unroll
  for (int i=0;i<8;i++){
    int idx = i*256 + t; int c = idx>>4, seg = idx&15;
    float4 v = *(const float4*)(h1 + (size_t)(b*NC+c)*HW + pbase + seg*4);
    ushort4 pk = make_ushort4(f2b(v.x), f2b(v.y), f2b(v.z), f2b(v.w));
    *(ushort4*)&Bw[c*68 + seg*4] = pk;
  }
  __syncthreads();
  int w = rfl(t>>6); int l = t&63; int q = l>>4; int ln = l&15;
  v4f acc[8];
  #pragma unroll
  for (int mt=0;mt<8;mt++) acc[mt] = (v4f){0.f,0.f,0.f,0.f};
  #pragma unroll
  for (int ks=0;ks<4;ks++){
    short8 bf;
    #pragma unroll
    for (int j=0;j<8;j++) bf[j] = Bw[(ks*32 + q*8 + j)*68 + w*16 + ln];
    #pragma unroll
    for (int mt=0;mt<8;mt++){
      short8 af = *(short8*)&Aw[(mt*16+ln)*136 + ks*32 + q*8];
      acc[mt] = __builtin_amdgcn_mfma_f32_16x16x32_bf16(af, bf, acc[mt], 0,0,0);
    }
  }
  int px = pbase + w*16 + ln;
  #pragma unroll
  for (int mt=0;mt<8;mt++){
    #pragma unroll
    for (int r=0;r<4;r++){
      int o = mt*16 + q*4 + r;
      h2[(size_t)(b*NC+o)*HW + px] = acc[mt][r] + pw_b[o];
    }
  }
}

// ---------------- K3: InstanceNorm stats ----------------
__global__ __launch_bounds__(256) void inorm_stats(const float* __restrict__ h2, float* __restrict__ st){
  int bc = blockIdx.x;
  const float* src = h2 + (size_t)bc*HW;
  float s=0.f, ss=0.f;
  for (int i=threadIdx.x; i<HW; i+=256){ float v=src[i]; s+=v; ss=fmaf(v,v,ss); }
  #pragma unroll
  for (int off=32; off; off>>=1){ s += __shfl_down(s,off); ss += __shfl_down(ss,off); }
  __shared__ float rsm[2][4];
  int wave = threadIdx.x>>6, lane = threadIdx.x&63;
  if (lane==0){ rsm[0][wave]=s; rsm[1][wave]=ss; }
  __syncthreads();
  if (threadIdx.x==0){
    float S = rsm[0][0]+rsm[0][1]+rsm[0][2]+rsm[0][3];
    float SS= rsm[1][0]+rsm[1][1]+rsm[1][2]+rsm[1][3];
    float mu = S * (1.f/9216.f);
    float var = SS * (1.f/9216.f) - mu*mu;
    st[bc*2]   = mu;
    st[bc*2+1] = rsqrtf(var + 1e-5f);
  }
}

// ---------------- K4: dsc (NCHW fp32) + dscT/dscL (NHWC bf16 hi/lo) ----------------
__global__ __launch_bounds__(256) void make_dsc(const float* __restrict__ h2,
    const float* __restrict__ st, float* __restrict__ dsc,
    u16* __restrict__ dscT, u16* __restrict__ dscL){
  int blk = blockIdx.x;
  int pt = blk % 144; int r = blk/144; int ch = r & 1; int b = r >> 1;
  int c0 = ch*64, pbase = pt*64;
  __shared__ float tile[64][65];
  int tr = threadIdx.x >> 2;
  int g  = threadIdx.x & 3;
  int c  = c0 + tr;
  float mu = st[(b*128+c)*2];
  float rs = st[(b*128+c)*2+1];
  const float* src = h2 + (size_t)(b*128+c)*HW + pbase + g*16;
  float* d = dsc + (size_t)(b*128+c)*HW + pbase + g*16;
  #pragma unroll
  for (int i=0;i<4;i++){
    float4 v = *(const float4*)(src + i*4);
    v.x=(v.x-mu)*rs; v.y=(v.y-mu)*rs; v.z=(v.z-mu)*rs; v.w=(v.w-mu)*rs;
    *(float4*)(d + i*4) = v;
    tile[tr][g*16+i*4+0]=v.x; tile[tr][g*16+i*4+1]=v.y;
    tile[tr][g*16+i*4+2]=v.z; tile[tr][g*16+i*4+3]=v.w;
  }
  __syncthreads();
  int pr = tr;
  u16* dt = dscT + ((size_t)b*HW + pbase + pr)*NC + c0 + g*16;
  u16* dl = dscL + ((size_t)b*HW + pbase + pr)*NC + c0 + g*16;
  #pragma unroll
  for (int i=0;i<4;i++){
    float v0 = tile[g*16+i*4+0][pr], v1 = tile[g*16+i*4+1][pr];
    float v2 = tile[g*16+i*4+2][pr], v3 = tile[g*16+i*4+3][pr];
    ushort4 hi = make_ushort4(f2b(v0), f2b(v1), f2b(v2), f2b(v3));
    ushort4 lo = make_ushort4(f2b(v0-bu2f(hi.x)), f2b(v1-bu2f(hi.y)),
                              f2b(v2-bu2f(hi.z)), f2b(v3-bu2f(hi.w)));
    *(ushort4*)(dt + i*4) = hi;
    *(ushort4*)(dl + i*4) = lo;
  }
}

// ---------------- K5: offset conv, round-6 protocol + 2-deep issue pipeline ------------
// Identical LDS protocol/barriers as round 6 (single As/Bs, commit between barriers).
// Only change: loads for step s+2 issue at top of step s via two named register sets.
__global__ __launch_bounds__(256) void off_mfma(const u16* __restrict__ dscT,
    const u16* __restrict__ dscL, const u16* __restrict__ wob,
    const float* __restrict__ off_b, float4* __restrict__ wg, ushort4* __restrict__ ad){
  __shared__ short As[2][32*40];             // hi/lo A tiles (32 px x 32 K)
  __shared__ short Bs[32*40];                // W tile (32 o x 32 K)
  __shared__ float Po[18*32];
  int blk = blockIdx.x;                      // 1152 = 8 * 144
  int tile = (blk&7)*144 + (blk>>3);
  int row0 = tile*32;
  int b = rfl(row0/HW); int pbase = rfl(row0 - b*HW);
  int t = threadIdx.x;
  int apx = t>>3, hl = (t>>2)&1, segA = t&3;
  int bo = t>>3, bsegB = t&7;
  int w = rfl(t>>6); int l = t&63; int q = l>>4; int ln = l&15;
  int mt = w&1, ntl = w>>1;
  int P = pbase + apx;
  int py = P/96, px_ = P - 96*(P/96);
  const u16* gsrc = (hl ? dscL : dscT) + (size_t)b*HW*NC;
  uint4 rgA, rgB; ushort4 wbA, wbB;
  auto issue = [&](int s, uint4& rg, ushort4& wb){
    int k = s>>2, cseg = s&3;
    int y2 = py + k/3 - 1, x2 = px_ + k%3 - 1;
    bool valid = ((unsigned)y2 < 96u) && ((unsigned)x2 < 96u);
    int off = ((y2*96 + x2)*NC) + cseg*32 + segA*8;
    rg = valid ? *(const uint4*)(gsrc + off) : (uint4){0,0,0,0};
    wb = *(const ushort4*)(wob + bo*1152 + k*128 + cseg*32 + bsegB*4);
  };
  auto commit = [&](uint4& rg, ushort4& wb){
    *(short8*)&As[hl][apx*40 + segA*8] = *(short8*)&rg;
    *(ushort4*)&Bs[bo*40 + bsegB*4] = wb;
  };
  v4f acc = (v4f){0.f,0.f,0.f,0.f};
  auto step = [&](){
    short8 ah = *(short8*)&As[0][(mt*16+ln)*40 + q*8];
    short8 al = *(short8*)&As[1][(mt*16+ln)*40 + q*8];
    short8 bf = *(short8*)&Bs[(ntl*16+ln)*40 + q*8];
    acc = __builtin_amdgcn_mfma_f32_16x16x32_bf16(ah, bf, acc, 0,0,0);
    acc = __builtin_amdgcn_mfma_f32_16x16x32_bf16(al, bf, acc, 0,0,0);
  };
  issue(0, rgA, wbA); issue(1, rgB, wbB);
  commit(rgA, wbA);
  __syncthreads();
  #pragma unroll 1
  for (int s=0;s<36;s+=2){
    if (s+2<36) issue(s+2, rgA, wbA);
    step();                                  // MFMA(s)
    __syncthreads();
    commit(rgB, wbB);                        // stage s+1 (s+1<36 always, s<=34)
    __syncthreads();
    if (s+3<36) issue(s+3, rgB, wbB);
    step();                                  // MFMA(s+1)
    __syncthreads();
    if (s+2<36){ commit(rgA, wbA); __syncthreads(); }
  }
  int o = ntl*16 + ln;
  if (o < 18){
    float ob = off_b[o];
    #pragma unroll
    for (int r=0;r<4;r++) Po[o*32 + mt*16 + q*4 + r] = acc[r] + ob;
  }
  __syncthreads();
  #pragma unroll
  for (int i=0;i<2;i++){
    int idx = i*256 + t;
    if (idx < 288){
      int pxl = idx & 31, k = idx >> 5;
      int Pp = pbase + pxl;
      float dy = Po[(2*k)*32 + pxl], dx = Po[(2*k+1)*32 + pxl];
      float ys = (float)(Pp/96 + k/3 - 1) + dy;
      float xs = (float)(Pp%96 + k%3 - 1) + dx;
      float fy0 = floorf(ys), fx0 = floorf(xs);
      float wy = ys - fy0, wx = xs - fx0;
      int y0 = (int)fy0, x0 = (int)fx0;
      int y1 = y0+1, x1 = x0+1;
      float vy0 = (y0>=0 && y0<=95) ? 1.f : 0.f;
      float vy1 = (y1>=0 && y1<=95) ? 1.f : 0.f;
      float vx0 = (x0>=0 && x0<=95) ? 1.f : 0.f;
      float vx1 = (x1>=0 && x1<=95) ? 1.f : 0.f;
      int y0c=min(max(y0,0),95), y1c=min(max(y1,0),95);
      int x0c=min(max(x0,0),95), x1c=min(max(x1,0),95);
      float4 w4;
      w4.x = (1.f-wy)*(1.f-wx)*vy0*vx0;
      w4.y = (1.f-wy)*wx*vy0*vx1;
      w4.z = wy*(1.f-wx)*vy1*vx0;
      w4.w = wy*wx*vy1*vx1;
      int gi = (b*9 + k)*HW + pbase + pxl;
      wg[gi] = w4;
      ad[gi] = make_ushort4((u16)(y0c*WD+x0c), (u16)(y0c*WD+x1c),
                            (u16)(y1c*WD+x0c), (u16)(y1c*WD+x1c));
    }
  }
}

// ---------------- K6: deform conv, round-6 protocol + wg/ad LDS + 2-deep pipeline ------
// Same As/Bs single-buffer barrier protocol as round 6. Changes: (1) wg/ad preloaded
// into LDS once (indirection off the chain); (2) gather+B loads for step s+2 issue at
// step s via two named register sets. B staging stays cooperative/coalesced.
__global__ __launch_bounds__(256) void deform_mfma(const u16* __restrict__ dscT,
    const u16* __restrict__ wdcb, const float* __restrict__ dc_b,
    const float4* __restrict__ wg, const ushort4* __restrict__ ad,
    float* __restrict__ dc_t){
  __shared__ short As[32*72];                // 32 px x 64 K (pad 72)
  __shared__ short Bs[128*72];               // 128 o x 64 K
  __shared__ float4 WgL[288];                // [tap*32+px]
  __shared__ ushort4 AdL[288];
  int blk = blockIdx.x;                      // 1152 = 8 * 144
  int tile = (blk&7)*144 + (blk>>3);
  int row0 = tile*32;
  int b = rfl(row0/HW); int pbase = rfl(row0 - b*HW);
  int t = threadIdx.x;
  int apx = t>>3, cs8 = t&7;
  int brow = t>>1, bs32 = (t&1)*32;
  int w = rfl(t>>6); int l = t&63; int q = l>>4; int ln = l&15;
  int mt = w&1, nb = (w>>1)*4;
  const u16* db0 = dscT + (size_t)b*HW*NC + cs8*8;
  #pragma unroll
  for (int i=0;i<2;i++){
    int idx = i*256 + t;
    if (idx < 288){ int k = idx>>5, pxl = idx&31; int gi = (b*9+k)*HW + pbase + pxl;
      WgL[idx] = wg[gi]; AdL[idx] = ad[gi]; }
  }
  __syncthreads();
  uint4 gA0,gA1,gA2,gA3, gB0,gB1,gB2,gB3;
  uint4 wA0,wA1,wA2,wA3, wB0,wB1,wB2,wB3;
  float4 wvA, wvB;
  auto issueG = [&](int s, float4& wv, uint4& r0, uint4& r1, uint4& r2, uint4& r3){
    int k = s>>1, cb = (s&1)<<6;
    ushort4 av = AdL[k*32+apx]; wv = WgL[k*32+apx];
    const u16* db = db0 + cb;
    r0 = *(const uint4*)(db + (int)av.x*NC);
    r1 = *(const uint4*)(db + (int)av.y*NC);
    r2 = *(const uint4*)(db + (int)av.z*NC);
    r3 = *(const uint4*)(db + (int)av.w*NC);
  };
  auto issueB = [&](int s, uint4& w0, uint4& w1, uint4& w2, uint4& w3){
    const u16* wp = wdcb + brow*1152 + (s>>1)*128 + ((s&1)<<6) + bs32;
    w0 = *(const uint4*)(wp);
    w1 = *(const uint4*)(wp + 8);
    w2 = *(const uint4*)(wp + 16);
    w3 = *(const uint4*)(wp + 24);
  };
  auto commitAB = [&](float4 wv, uint4& r0, uint4& r1, uint4& r2, uint4& r3,
                      uint4& w0, uint4& w1, uint4& w2, uint4& w3){
    const u16* pa=(const u16*)&r0; const u16* pb=(const u16*)&r1;
    const u16* pc=(const u16*)&r2; const u16* pd=(const u16*)&r3;
    short8 sv;
    #pragma unroll
    for (int j=0;j<8;j++){
      float f = wv.x*bu2f(pa[j]) + wv.y*bu2f(pb[j]) + wv.z*bu2f(pc[j]) + wv.w*bu2f(pd[j]);
      sv[j] = (short)f2b(f);
    }
    *(short8*)&As[apx*72 + cs8*8] = sv;
    *(short8*)&Bs[brow*72 + bs32 +  0] = *(short8*)&w0;
    *(short8*)&Bs[brow*72 + bs32 +  8] = *(short8*)&w1;
    *(short8*)&Bs[brow*72 + bs32 + 16] = *(short8*)&w2;
    *(short8*)&Bs[brow*72 + bs32 + 24] = *(short8*)&w3;
  };
  v4f acc[4];
  #pragma unroll
  for (int nt=0;nt<4;nt++) acc[nt] = (v4f){0.f,0.f,0.f,0.f};
  auto step = [&](){
    #pragma unroll
    for (int ks=0;ks<2;ks++){
      short8 af = *(const short8*)&As[(mt*16+ln)*72 + ks*32 + q*8];
      #pragma unroll
      for (int nt=0;nt<4;nt++){
        short8 bf = *(const short8*)&Bs[((nb+nt)*16+ln)*72 + ks*32 + q*8];
        acc[nt] = __builtin_amdgcn_mfma_f32_16x16x32_bf16(af, bf, acc[nt], 0,0,0);
      }
    }
  };
  issueG(0, wvA, gA0,gA1,gA2,gA3); issueB(0, wA0,wA1,wA2,wA3);
  issueG(1, wvB, gB0,gB1,gB2,gB3); issueB(1, wB0,wB1,wB2,wB3);
  commitAB(wvA, gA0,gA1,gA2,gA3, wA0,wA1,wA2,wA3);
  __syncthreads();
  #pragma unroll 1
  for (int s=0;s<18;s+=2){
    if (s+2<18){ issueG(s+2, wvA, gA0,gA1,gA2,gA3); issueB(s+2, wA0,wA1,wA2,wA3); }
    step();                                  // MFMA(s)
    __syncthreads();
    commitAB(wvB, gB0,gB1,gB2,gB3, wB0,wB1,wB2,wB3);   // stage s+1 (s<=16 -> s+1<18)
    __syncthreads();
    if (s+3<18){ issueG(s+3, wvB, gB0,gB1,gB2,gB3); issueB(s+3, wB0,wB1,wB2,wB3); }
    step();                                  // MFMA(s+1)
    __syncthreads();
    if (s+2<18){ commitAB(wvA, gA0,gA1,gA2,gA3, wA0,wA1,wA2,wA3); __syncthreads(); }
  }
  #pragma unroll
  for (int nt=0;nt<4;nt++){
    int o = (nb+nt)*16 + ln;
    float bias = dc_b[o];
    #pragma unroll
    for (int r=0;r<4;r++){
      int px = pbase + mt*16 + q*4 + r;
      dc_t[((size_t)b*HW + px)*NC + o] = acc[nt][r] + bias;
    }
  }
}

// ---------------- K7: channel LayerNorm + sigmoid gate + multiply ----------------
__global__ __launch_bounds__(256) void epilogue(const float* __restrict__ dc_t,
    const float* __restrict__ dsc, const float* __restrict__ ln_g,
    const float* __restrict__ ln_b, float* __restrict__ out){
  __shared__ float T[64*129];
  __shared__ float Ps[4*64], Qs[4*64], Ms[64], Rs[64];
  int blk = blockIdx.x;
  int b = rfl(blk/144); int pbase = rfl(blk - (blk/144)*144)*64;
  int t = threadIdx.x;
  #pragma unroll
  for (int i=0;i<8;i++){
    int idx = i*256 + t; int px = idx>>5, seg = idx&31;
    float4 v = *(const float4*)(dc_t + ((size_t)b*HW + pbase + px)*NC + seg*4);
    float* d = &T[px*129 + seg*4];
    d[0]=v.x; d[1]=v.y; d[2]=v.z; d[3]=v.w;
  }
  __syncthreads();
  int px = t&63, cg = t>>6;
  float s=0.f, ss=0.f;
  #pragma unroll
  for (int i=0;i<32;i++){ float v = T[px*129 + cg*32 + i]; s += v; ss = fmaf(v,v,ss); }
  Ps[cg*64+px] = s; Qs[cg*64+px] = ss;
  __syncthreads();
  if (t<64){
    float S = Ps[px]+Ps[64+px]+Ps[128+px]+Ps[192+px];
    float SS= Qs[px]+Qs[64+px]+Qs[128+px]+Qs[192+px];
    float m = S*(1.f/128.f);
    float var = SS*(1.f/128.f) - m*m;
    Ms[px] = m; Rs[px] = rsqrtf(var + 1e-5f);
  }
  __syncthreads();
  float m = Ms[px], rs = Rs[px];
  #pragma unroll 4
  for (int i=0;i<32;i++){
    int c = cg*32 + i;
    float ln = (T[px*129+c] - m)*rs*ln_g[c] + ln_b[c];
    float attn = 1.f/(1.f+__expf(-ln));
    size_t idx = (size_t)(b*NC+c)*HW + pbase + px;
    out[idx] = dsc[idx]*attn;
  }
}

extern "C" void kernel_launch(void* const* d_in, const int* in_sizes, int n_in,
                              void* d_out, int out_size, void* d_ws, size_t ws_size,
                              hipStream_t stream){
  const float* x    = (const float*)d_in[0];
  const float* dw_w = (const float*)d_in[1];
  const float* dw_b = (const float*)d_in[2];
  const float* pw_w = (const float*)d_in[3];
  const float* pw_b = (const float*)d_in[4];
  const float* off_w= (const float*)d_in[5];
  const float* off_b= (const float*)d_in[6];
  const float* dc_w = (const float*)d_in[7];
  const float* dc_b = (const float*)d_in[8];
  const float* ln_g = (const float*)d_in[9];
  const float* ln_b = (const float*)d_in[10];
  float* out = (float*)d_out;

  float* W    = (float*)d_ws;
  float*   bufA = W;                          // h1, then dsc (NCHW f32)
  float*   bufB = W + 4718592;                // h2, then dc_t (NHWC f32)
  u16*     dscT = (u16*)(W + 9437184);        // NHWC bf16 hi (4718592 u16)
  u16*     dscL = (u16*)(W + 11796480);       // NHWC bf16 lo residual
  float4*  wg   = (float4*)(W + 14155776);    // 331776 float4
  ushort4* ad   = (ushort4*)(W + 15482880);   // 331776 ushort4
  float*   st   = W + 16146432;
  u16*     wpwb = (u16*)(W + 16147456);       // 16384 u16
  u16*     wob  = (u16*)(W + 16155648);       // 36864 u16
  u16*     wdcb = (u16*)(W + 16174080);       // 147456 u16

  prep_weights<<<576, 256, 0, stream>>>(pw_w, off_w, dc_w, wpwb, wob, wdcb);
  dw_conv     <<<18432, 256, 0, stream>>>(x, dw_w, dw_b, bufA);
  pw_mfma     <<<576, 256, 0, stream>>>(bufA, wpwb, pw_b, bufB);
  inorm_stats <<<512, 256, 0, stream>>>(bufB, st);
  make_dsc    <<<1152, 256, 0, stream>>>(bufB, st, bufA, dscT, dscL);
  off_mfma    <<<1152, 256, 0, stream>>>(dscT, dscL, wob, off_b, wg, ad);
  deform_mfma <<<1152, 256, 0, stream>>>(dscT, wdcb, dc_b, wg, ad, bufB);
  epilogue    <<<576, 256, 0, stream>>>(bufB, bufA, ln_g, ln_b, out);
}